// Round 1
// baseline (1139.170 us; speedup 1.0000x reference)
//
#include <hip/hip_runtime.h>

#define BN_EPS 1e-5f

// ---------------- utility kernels ----------------

__global__ void k_fill1(float* __restrict__ p, int n) {
  int i = blockIdx.x * blockDim.x + threadIdx.x;
  if (i < n) p[i] = 1.0f;   // self-loop contributes 1 to every node's degree
}

__global__ void k_zero(float* __restrict__ p, int n) {
  int i = blockIdx.x * blockDim.x + threadIdx.x;
  if (i < n) p[i] = 0.0f;
}

__global__ void k_deg(const int* __restrict__ dst, float* __restrict__ deg, int E) {
  int e = blockIdx.x * blockDim.x + threadIdx.x;
  if (e < E) atomicAdd(&deg[dst[e]], 1.0f);
}

__global__ void k_dinv(float* __restrict__ p, int n) {
  int i = blockIdx.x * blockDim.x + threadIdx.x;
  if (i < n) p[i] = rsqrtf(p[i]);   // deg >= 1 always (self-loops)
}

// ---------------- GEMM: Y[n,64] = X[n,K] @ W[K,64] ----------------
// One thread per output element (j = lane). W staged in LDS (K*64*4 bytes).
// X row read as float4; all 64 lanes of a wave share the same row -> the
// global load address is wave-uniform (single transaction, L1 broadcast).
template<int K>
__global__ __launch_bounds__(256) void k_gemm(const float* __restrict__ X,
                                              const float* __restrict__ W,
                                              float* __restrict__ Y, int n) {
  __shared__ float Ws[K * 64];
  for (int t = threadIdx.x; t < K * 64; t += 256) Ws[t] = W[t];
  __syncthreads();
  int j = threadIdx.x & 63;
  int r = threadIdx.x >> 6;           // wave index in block: 0..3
  int i = blockIdx.x * 4 + r;         // row (node)
  if (i >= n) return;
  const float4* xv = (const float4*)(X + (size_t)i * K);
  float acc = 0.f;
#pragma unroll
  for (int k4 = 0; k4 < K / 4; ++k4) {
    float4 v = xv[k4];
    acc = fmaf(v.x, Ws[(4 * k4 + 0) * 64 + j], acc);
    acc = fmaf(v.y, Ws[(4 * k4 + 1) * 64 + j], acc);
    acc = fmaf(v.z, Ws[(4 * k4 + 2) * 64 + j], acc);
    acc = fmaf(v.w, Ws[(4 * k4 + 3) * 64 + j], acc);
  }
  Y[(size_t)i * 64 + j] = acc;
}

// out[i,j] = b[j] + H[i,j]*dinv[i]^2   (bias + self-loop term; initializes out)
__global__ __launch_bounds__(256) void k_initout(const float* __restrict__ H,
                                                 const float* __restrict__ dinv,
                                                 const float* __restrict__ b,
                                                 float* __restrict__ out, int n) {
  int j = threadIdx.x & 63;
  int i = blockIdx.x * 4 + (threadIdx.x >> 6);
  if (i >= n) return;
  float di = dinv[i];
  out[(size_t)i * 64 + j] = b[j] + H[(size_t)i * 64 + j] * di * di;
}

// edge scatter: out[dst] += H[src] * dinv[src]*dinv[dst]; one wave per edge
__global__ __launch_bounds__(256) void k_scatter(const float* __restrict__ H,
                                                 const int* __restrict__ src,
                                                 const int* __restrict__ dst,
                                                 const float* __restrict__ dinv,
                                                 float* __restrict__ out, int E) {
  int e = blockIdx.x * 4 + (threadIdx.x >> 6);
  int j = threadIdx.x & 63;
  if (e >= E) return;
  int s = src[e];
  int d = dst[e];
  float nrm = dinv[s] * dinv[d];
  float v = H[(size_t)s * 64 + j] * nrm;
  atomicAdd(&out[(size_t)d * 64 + j], v);
}

// BN stats: stats[0..63] = column sums, stats[64..127] = column sum-of-squares
__global__ __launch_bounds__(256) void k_bnstats(const float* __restrict__ A,
                                                 float* __restrict__ stats, int n) {
  int j = threadIdx.x & 63;
  int r = threadIdx.x >> 6;
  float s = 0.f, s2 = 0.f;
  for (int i = blockIdx.x * 4 + r; i < n; i += gridDim.x * 4) {
    float v = A[(size_t)i * 64 + j];
    s += v;
    s2 += v * v;
  }
  __shared__ float ls[256], ls2[256];
  ls[threadIdx.x] = s;
  ls2[threadIdx.x] = s2;
  __syncthreads();
  if (threadIdx.x < 64) {
    float ts = ls[j] + ls[j + 64] + ls[j + 128] + ls[j + 192];
    float ts2 = ls2[j] + ls2[j + 64] + ls2[j + 128] + ls2[j + 192];
    atomicAdd(&stats[j], ts);
    atomicAdd(&stats[64 + j], ts2);
  }
}

// BN apply + ReLU: Hout = relu((A - mean)*rsqrt(var+eps)*gamma + beta)
__global__ __launch_bounds__(256) void k_bnapply(const float* __restrict__ A,
                                                 const float* __restrict__ stats,
                                                 const float* __restrict__ gamma,
                                                 const float* __restrict__ beta,
                                                 float* __restrict__ Hout, int n) {
  int j = threadIdx.x & 63;
  int i = blockIdx.x * 4 + (threadIdx.x >> 6);
  if (i >= n) return;
  float inv_n = 1.0f / (float)n;
  float mean = stats[j] * inv_n;
  float var = stats[64 + j] * inv_n - mean * mean;
  float scale = rsqrtf(var + BN_EPS) * gamma[j];
  float v = (A[(size_t)i * 64 + j] - mean) * scale + beta[j];
  Hout[(size_t)i * 64 + j] = fmaxf(v, 0.f);
}

// ---------------- launch ----------------

extern "C" void kernel_launch(void* const* d_in, const int* in_sizes, int n_in,
                              void* d_out, int out_size, void* d_ws, size_t ws_size,
                              hipStream_t stream) {
  const float* x     = (const float*)d_in[0];
  const int*   ei    = (const int*)d_in[1];
  const float* W1    = (const float*)d_in[2];
  const float* b1    = (const float*)d_in[3];
  const float* W2    = (const float*)d_in[4];
  const float* b2    = (const float*)d_in[5];
  const float* gamma = (const float*)d_in[6];
  const float* beta  = (const float*)d_in[7];
  float* out = (float*)d_out;

  const int N = in_sizes[0] / 128;   // 100000
  const int E = in_sizes[1] / 2;     // 1600000
  const int* src = ei;
  const int* dst = ei + E;

  // workspace layout (floats)
  float* dinv  = (float*)d_ws;                          // N (deg -> dinv in place)
  float* h     = dinv + (((size_t)N + 255) & ~(size_t)255);
  float* agg   = h + (size_t)N * 64;
  float* stats = agg + (size_t)N * 64;                  // 128

  int nb_n   = (N + 255) / 256;
  int nb_e   = (E + 255) / 256;
  int nb_n4  = (N + 3) / 4;
  int nb_e4  = (E + 3) / 4;

  // degree (incl. self-loop) -> dinv
  k_fill1<<<nb_n, 256, 0, stream>>>(dinv, N);
  k_deg<<<nb_e, 256, 0, stream>>>(dst, dinv, E);
  k_dinv<<<nb_n, 256, 0, stream>>>(dinv, N);

  // layer 1: h = x @ W1 ; agg = b1 + selfloop + edge scatter
  k_gemm<128><<<nb_n4, 256, 0, stream>>>(x, W1, h, N);
  k_initout<<<nb_n4, 256, 0, stream>>>(h, dinv, b1, agg, N);
  k_scatter<<<nb_e4, 256, 0, stream>>>(h, src, dst, dinv, agg, E);

  // batchnorm (batch stats) + relu -> h (reused as h2)
  k_zero<<<1, 128, 0, stream>>>(stats, 128);
  k_bnstats<<<1024, 256, 0, stream>>>(agg, stats, N);
  k_bnapply<<<nb_n4, 256, 0, stream>>>(agg, stats, gamma, beta, h, N);

  // layer 2: g = h2 @ W2 -> agg ; out = b2 + selfloop + edge scatter
  k_gemm<64><<<nb_n4, 256, 0, stream>>>(h, W2, agg, N);
  k_initout<<<nb_n4, 256, 0, stream>>>(agg, dinv, b2, out, N);
  k_scatter<<<nb_e4, 256, 0, stream>>>(agg, src, dst, dinv, out, E);
}

// Round 2
// 695.576 us; speedup vs baseline: 1.6377x; 1.6377x over previous
//
#include <hip/hip_runtime.h>

#define BN_EPS 1e-5f
#define SCAN_CHUNK 2048

// ---------------- utility ----------------

__global__ void k_zero_int(int* __restrict__ p, int n) {
  int i = blockIdx.x * blockDim.x + threadIdx.x;
  if (i < n) p[i] = 0;
}

__global__ void k_zero_f(float* __restrict__ p, int n) {
  int i = blockIdx.x * blockDim.x + threadIdx.x;
  if (i < n) p[i] = 0.0f;
}

__global__ void k_deg_int(const int* __restrict__ dst, int* __restrict__ cnt, int E) {
  int e = blockIdx.x * blockDim.x + threadIdx.x;
  if (e < E) atomicAdd(&cnt[dst[e]], 1);
}

// dinv[i] = rsqrt(1 + deg[i])  (self-loop included)
__global__ void k_dinv(const int* __restrict__ cnt, float* __restrict__ dinv, int n) {
  int i = blockIdx.x * blockDim.x + threadIdx.x;
  if (i < n) dinv[i] = rsqrtf(1.0f + (float)cnt[i]);
}

// ---------------- exclusive scan (deg -> row_ptr) ----------------

__global__ __launch_bounds__(256) void k_scan_local(const int* __restrict__ deg,
                                                    int* __restrict__ row_ptr,
                                                    int* __restrict__ blksum, int n) {
  __shared__ int ts[256];
  int base = blockIdx.x * SCAN_CHUNK;
  int t = threadIdx.x;
  int idx0 = base + t * 8;
  int v[8];
  int s = 0;
#pragma unroll
  for (int k = 0; k < 8; ++k) {
    int i = idx0 + k;
    int d = (i < n) ? deg[i] : 0;
    v[k] = s;                       // exclusive within thread
    s += d;
  }
  int val = s;
  ts[t] = val;
  __syncthreads();
#pragma unroll
  for (int off = 1; off < 256; off <<= 1) {
    int add = (t >= off) ? ts[t - off] : 0;
    __syncthreads();
    val += add;
    ts[t] = val;
    __syncthreads();
  }
  int excl = val - s;               // exclusive prefix of this thread within block
#pragma unroll
  for (int k = 0; k < 8; ++k) {
    int i = idx0 + k;
    if (i < n) row_ptr[i] = excl + v[k];
  }
  if (t == 255) blksum[blockIdx.x] = val;   // block total
}

__global__ void k_scan_blk(int* __restrict__ blksum, int nblk,
                           int* __restrict__ row_ptr, int n) {
  if (threadIdx.x == 0) {
    int run = 0;
    for (int i = 0; i < nblk; ++i) { int v = blksum[i]; blksum[i] = run; run += v; }
    row_ptr[n] = run;               // == E
  }
}

__global__ __launch_bounds__(256) void k_scan_add(int* __restrict__ row_ptr,
                                                  const int* __restrict__ blksum, int n) {
  int off = blksum[blockIdx.x];
  int base = blockIdx.x * SCAN_CHUNK;
  for (int k = threadIdx.x; k < SCAN_CHUNK; k += 256) {
    int i = base + k;
    if (i < n) row_ptr[i] += off;
  }
}

// CSR fill: col[pos]=src, w[pos]=dinv[src]*dinv[dst]
__global__ void k_fill(const int* __restrict__ src, const int* __restrict__ dst,
                       const float* __restrict__ dinv, const int* __restrict__ row_ptr,
                       int* __restrict__ fill, int* __restrict__ col,
                       float* __restrict__ w, int E) {
  int e = blockIdx.x * blockDim.x + threadIdx.x;
  if (e >= E) return;
  int s = src[e], d = dst[e];
  int pos = row_ptr[d] + atomicAdd(&fill[d], 1);
  col[pos] = s;
  w[pos] = dinv[s] * dinv[d];
}

// ---------------- GEMM: Y[n,64] = X[n,K] @ W[K,64] ----------------
template<int K>
__global__ __launch_bounds__(256) void k_gemm(const float* __restrict__ X,
                                              const float* __restrict__ W,
                                              float* __restrict__ Y, int n) {
  __shared__ float Ws[K * 64];
  for (int t = threadIdx.x; t < K * 64; t += 256) Ws[t] = W[t];
  __syncthreads();
  int j = threadIdx.x & 63;
  int r = threadIdx.x >> 6;
  int i = blockIdx.x * 4 + r;
  if (i >= n) return;
  const float4* xv = (const float4*)(X + (size_t)i * K);
  float acc = 0.f;
#pragma unroll
  for (int k4 = 0; k4 < K / 4; ++k4) {
    float4 v = xv[k4];
    acc = fmaf(v.x, Ws[(4 * k4 + 0) * 64 + j], acc);
    acc = fmaf(v.y, Ws[(4 * k4 + 1) * 64 + j], acc);
    acc = fmaf(v.z, Ws[(4 * k4 + 2) * 64 + j], acc);
    acc = fmaf(v.w, Ws[(4 * k4 + 3) * 64 + j], acc);
  }
  Y[(size_t)i * 64 + j] = acc;
}

// ---------------- CSR gather aggregation ----------------
// out[i,j] = b[j] + H[i,j]*dinv[i]^2 + sum_p H[col[p],j]*w[p]
__global__ __launch_bounds__(256) void k_gather(const float* __restrict__ H,
                                                const int* __restrict__ row_ptr,
                                                const int* __restrict__ col,
                                                const float* __restrict__ w,
                                                const float* __restrict__ dinv,
                                                const float* __restrict__ b,
                                                float* __restrict__ out, int n) {
  int j = threadIdx.x & 63;
  int i = blockIdx.x * 4 + (threadIdx.x >> 6);
  if (i >= n) return;
  float di = dinv[i];
  float acc = b[j] + H[(size_t)i * 64 + j] * di * di;
  int p0 = row_ptr[i], p1 = row_ptr[i + 1];
  int p = p0;
  for (; p + 1 < p1; p += 2) {
    int s0 = col[p], s1 = col[p + 1];
    float w0 = w[p], w1 = w[p + 1];
    float h0 = H[(size_t)s0 * 64 + j];
    float h1 = H[(size_t)s1 * 64 + j];
    acc = fmaf(h0, w0, acc);
    acc = fmaf(h1, w1, acc);
  }
  if (p < p1) {
    acc = fmaf(H[(size_t)col[p] * 64 + j], w[p], acc);
  }
  out[(size_t)i * 64 + j] = acc;
}

// ---------------- BatchNorm ----------------

__global__ __launch_bounds__(256) void k_bnstats(const float* __restrict__ A,
                                                 float* __restrict__ stats, int n) {
  int j = threadIdx.x & 63;
  int r = threadIdx.x >> 6;
  float s = 0.f, s2 = 0.f;
  for (int i = blockIdx.x * 4 + r; i < n; i += gridDim.x * 4) {
    float v = A[(size_t)i * 64 + j];
    s += v;
    s2 += v * v;
  }
  __shared__ float ls[256], ls2[256];
  ls[threadIdx.x] = s;
  ls2[threadIdx.x] = s2;
  __syncthreads();
  if (threadIdx.x < 64) {
    float ts = ls[j] + ls[j + 64] + ls[j + 128] + ls[j + 192];
    float ts2 = ls2[j] + ls2[j + 64] + ls2[j + 128] + ls2[j + 192];
    atomicAdd(&stats[j], ts);
    atomicAdd(&stats[64 + j], ts2);
  }
}

__global__ __launch_bounds__(256) void k_bnapply(const float* __restrict__ A,
                                                 const float* __restrict__ stats,
                                                 const float* __restrict__ gamma,
                                                 const float* __restrict__ beta,
                                                 float* __restrict__ Hout, int n) {
  int j = threadIdx.x & 63;
  int i = blockIdx.x * 4 + (threadIdx.x >> 6);
  if (i >= n) return;
  float inv_n = 1.0f / (float)n;
  float mean = stats[j] * inv_n;
  float var = stats[64 + j] * inv_n - mean * mean;
  float scale = rsqrtf(var + BN_EPS) * gamma[j];
  float v = (A[(size_t)i * 64 + j] - mean) * scale + beta[j];
  Hout[(size_t)i * 64 + j] = fmaxf(v, 0.f);
}

// ---------------- launch ----------------

extern "C" void kernel_launch(void* const* d_in, const int* in_sizes, int n_in,
                              void* d_out, int out_size, void* d_ws, size_t ws_size,
                              hipStream_t stream) {
  const float* x     = (const float*)d_in[0];
  const int*   ei    = (const int*)d_in[1];
  const float* W1    = (const float*)d_in[2];
  const float* b1    = (const float*)d_in[3];
  const float* W2    = (const float*)d_in[4];
  const float* b2    = (const float*)d_in[5];
  const float* gamma = (const float*)d_in[6];
  const float* beta  = (const float*)d_in[7];
  float* out = (float*)d_out;

  const int N = in_sizes[0] / 128;   // 100000
  const int E = in_sizes[1] / 2;     // 1600000
  const int* src = ei;
  const int* dst = ei + E;

  const size_t Npad = ((size_t)N + 256) & ~(size_t)255;  // room for row_ptr[N]

  // workspace layout
  char* p = (char*)d_ws;
  float* dinv    = (float*)p;               p += Npad * 4;
  int*   cnt     = (int*)p;                 p += Npad * 4;   // deg, then fill ctr
  int*   row_ptr = (int*)p;                 p += Npad * 4;
  int*   blksum  = (int*)p;                 p += 256 * 4;
  int*   col     = (int*)p;                 p += (size_t)E * 4;
  float* w       = (float*)p;               p += (size_t)E * 4;
  float* h       = (float*)p;               p += (size_t)N * 64 * 4;
  float* agg     = (float*)p;               p += (size_t)N * 64 * 4;
  float* stats   = (float*)p;               p += 128 * 4;

  int nb_n  = (N + 255) / 256;
  int nb_e  = (E + 255) / 256;
  int nb_n4 = (N + 3) / 4;
  int nscan = (N + SCAN_CHUNK - 1) / SCAN_CHUNK;

  // ---- degree + dinv ----
  k_zero_int<<<nb_n, 256, 0, stream>>>(cnt, N);
  k_deg_int<<<nb_e, 256, 0, stream>>>(dst, cnt, E);
  k_dinv<<<nb_n, 256, 0, stream>>>(cnt, dinv, N);

  // ---- CSR build: row_ptr = exclusive_scan(deg); fill col/w ----
  k_scan_local<<<nscan, 256, 0, stream>>>(cnt, row_ptr, blksum, N);
  k_scan_blk<<<1, 64, 0, stream>>>(blksum, nscan, row_ptr, N);
  k_scan_add<<<nscan, 256, 0, stream>>>(row_ptr, blksum, N);
  k_zero_int<<<nb_n, 256, 0, stream>>>(cnt, N);
  k_fill<<<nb_e, 256, 0, stream>>>(src, dst, dinv, row_ptr, cnt, col, w, E);

  // ---- layer 1 ----
  k_gemm<128><<<nb_n4, 256, 0, stream>>>(x, W1, h, N);
  k_gather<<<nb_n4, 256, 0, stream>>>(h, row_ptr, col, w, dinv, b1, agg, N);

  // ---- batchnorm + relu -> h (reused) ----
  k_zero_f<<<1, 128, 0, stream>>>(stats, 128);
  k_bnstats<<<1024, 256, 0, stream>>>(agg, stats, N);
  k_bnapply<<<nb_n4, 256, 0, stream>>>(agg, stats, gamma, beta, h, N);

  // ---- layer 2 ----
  k_gemm<64><<<nb_n4, 256, 0, stream>>>(h, W2, agg, N);
  k_gather<<<nb_n4, 256, 0, stream>>>(agg, row_ptr, col, w, dinv, b2, out, N);
}

// Round 3
// 500.814 us; speedup vs baseline: 2.2746x; 1.3889x over previous
//
#include <hip/hip_runtime.h>

#define BN_EPS 1e-5f
#define SCAN_CHUNK 2048

// ---------------- utility ----------------

__global__ void k_zero_int(int* __restrict__ p, int n) {
  int i = blockIdx.x * blockDim.x + threadIdx.x;
  if (i < n) p[i] = 0;
}

__global__ void k_zero_f(float* __restrict__ p, int n) {
  int i = blockIdx.x * blockDim.x + threadIdx.x;
  if (i < n) p[i] = 0.0f;
}

__global__ void k_deg_int(const int* __restrict__ dst, int* __restrict__ cnt, int E) {
  int e = blockIdx.x * blockDim.x + threadIdx.x;
  if (e < E) atomicAdd(&cnt[dst[e]], 1);
}

// dinv[i] = rsqrt(1 + deg[i])  (self-loop included)
__global__ void k_dinv(const int* __restrict__ cnt, float* __restrict__ dinv, int n) {
  int i = blockIdx.x * blockDim.x + threadIdx.x;
  if (i < n) dinv[i] = rsqrtf(1.0f + (float)cnt[i]);
}

// ---------------- exclusive scan (deg -> row_ptr) ----------------

__global__ __launch_bounds__(256) void k_scan_local(const int* __restrict__ deg,
                                                    int* __restrict__ row_ptr,
                                                    int* __restrict__ blksum, int n) {
  __shared__ int ts[256];
  int base = blockIdx.x * SCAN_CHUNK;
  int t = threadIdx.x;
  int idx0 = base + t * 8;
  int v[8];
  int s = 0;
#pragma unroll
  for (int k = 0; k < 8; ++k) {
    int i = idx0 + k;
    int d = (i < n) ? deg[i] : 0;
    v[k] = s;
    s += d;
  }
  int val = s;
  ts[t] = val;
  __syncthreads();
#pragma unroll
  for (int off = 1; off < 256; off <<= 1) {
    int add = (t >= off) ? ts[t - off] : 0;
    __syncthreads();
    val += add;
    ts[t] = val;
    __syncthreads();
  }
  int excl = val - s;
#pragma unroll
  for (int k = 0; k < 8; ++k) {
    int i = idx0 + k;
    if (i < n) row_ptr[i] = excl + v[k];
  }
  if (t == 255) blksum[blockIdx.x] = val;
}

__global__ void k_scan_blk(int* __restrict__ blksum, int nblk,
                           int* __restrict__ row_ptr, int n) {
  if (threadIdx.x == 0) {
    int run = 0;
    for (int i = 0; i < nblk; ++i) { int v = blksum[i]; blksum[i] = run; run += v; }
    row_ptr[n] = run;
  }
}

__global__ __launch_bounds__(256) void k_scan_add(int* __restrict__ row_ptr,
                                                  const int* __restrict__ blksum, int n) {
  int off = blksum[blockIdx.x];
  int base = blockIdx.x * SCAN_CHUNK;
  for (int k = threadIdx.x; k < SCAN_CHUNK; k += 256) {
    int i = base + k;
    if (i < n) row_ptr[i] += off;
  }
}

// CSR fill: ew[pos] = {src_bits, dinv[src]*dinv[dst]} as one 8B record
__global__ void k_fill(const int* __restrict__ src, const int* __restrict__ dst,
                       const float* __restrict__ dinv, const int* __restrict__ row_ptr,
                       int* __restrict__ fill, float2* __restrict__ ew, int E) {
  int e = blockIdx.x * blockDim.x + threadIdx.x;
  if (e >= E) return;
  int s = src[e], d = dst[e];
  int pos = row_ptr[d] + atomicAdd(&fill[d], 1);
  ew[pos] = make_float2(__int_as_float(s), dinv[s] * dinv[d]);
}

// ---------------- tiled GEMM: Y[n,64] = X[n,K] @ W[K,64] ----------------
// One block per 64-row tile. W (K x 64) + padded x-tile (64 x K+4) in LDS.
// Each thread computes a 4x4 register tile: tc = t&15 -> cols tc*4..+3,
// tr = t>>4 -> rows tr*4..+3. ds_read_b128 for both operands; x-tile row
// stride K+4 breaks the stride-128 4-way bank aliasing across row groups.
template<int K>
__global__ __launch_bounds__(256) void k_gemm(const float* __restrict__ X,
                                              const float* __restrict__ W,
                                              float* __restrict__ Y, int n) {
  constexpr int XS = K + 4;
  __shared__ float Ws[K * 64];
  __shared__ float Xs[64 * XS];

  const int t = threadIdx.x;
  const int base = blockIdx.x * 64;

  // stage W (coalesced float4)
  {
    const float4* wv = (const float4*)W;
    float4* wsv = (float4*)Ws;
#pragma unroll
    for (int idx = t; idx < K * 16; idx += 256) wsv[idx] = wv[idx];
  }
  // stage x tile (coalesced float4), zero-fill OOB rows
  {
    constexpr int RV = K / 4;  // float4 per row
    for (int idx = t; idx < 64 * RV; idx += 256) {
      int row = idx / RV, kk = idx % RV;
      float4 v = make_float4(0.f, 0.f, 0.f, 0.f);
      if (base + row < n) v = *(const float4*)(X + (size_t)(base + row) * K + kk * 4);
      *(float4*)(Xs + row * XS + kk * 4) = v;
    }
  }
  __syncthreads();

  const int tc = t & 15;   // col group
  const int tr = t >> 4;   // row group

  float acc[4][4];
#pragma unroll
  for (int r = 0; r < 4; ++r)
#pragma unroll
    for (int c = 0; c < 4; ++c) acc[r][c] = 0.f;

#pragma unroll 4
  for (int k = 0; k < K; k += 4) {
    float4 xr[4], wr[4];
#pragma unroll
    for (int r = 0; r < 4; ++r) xr[r] = *(const float4*)(Xs + (tr * 4 + r) * XS + k);
#pragma unroll
    for (int kk = 0; kk < 4; ++kk) wr[kk] = *(const float4*)(Ws + (k + kk) * 64 + tc * 4);
#pragma unroll
    for (int kk = 0; kk < 4; ++kk) {
#pragma unroll
      for (int r = 0; r < 4; ++r) {
        float xv = (kk == 0) ? xr[r].x : (kk == 1) ? xr[r].y : (kk == 2) ? xr[r].z : xr[r].w;
        acc[r][0] = fmaf(xv, wr[kk].x, acc[r][0]);
        acc[r][1] = fmaf(xv, wr[kk].y, acc[r][1]);
        acc[r][2] = fmaf(xv, wr[kk].z, acc[r][2]);
        acc[r][3] = fmaf(xv, wr[kk].w, acc[r][3]);
      }
    }
  }

#pragma unroll
  for (int r = 0; r < 4; ++r) {
    int i = base + tr * 4 + r;
    if (i < n) {
      float4 o = make_float4(acc[r][0], acc[r][1], acc[r][2], acc[r][3]);
      *(float4*)(Y + (size_t)i * 64 + tc * 4) = o;
    }
  }
}

// ---------------- CSR gather aggregation ----------------
// out[i,j] = b[j] + H[i,j]*dinv[i]^2 + sum_p H[col[p],j]*w[p]
__global__ __launch_bounds__(256) void k_gather(const float* __restrict__ H,
                                                const int* __restrict__ row_ptr,
                                                const float2* __restrict__ ew,
                                                const float* __restrict__ dinv,
                                                const float* __restrict__ b,
                                                float* __restrict__ out, int n) {
  int j = threadIdx.x & 63;
  int i = blockIdx.x * 4 + (threadIdx.x >> 6);
  if (i >= n) return;
  float di = dinv[i];
  float acc = b[j] + H[(size_t)i * 64 + j] * di * di;
  int p0 = row_ptr[i], p1 = row_ptr[i + 1];
  int p = p0;
  for (; p + 3 < p1; p += 4) {
    float2 e0 = ew[p], e1 = ew[p + 1], e2 = ew[p + 2], e3 = ew[p + 3];
    float h0 = H[(size_t)__float_as_int(e0.x) * 64 + j];
    float h1 = H[(size_t)__float_as_int(e1.x) * 64 + j];
    float h2 = H[(size_t)__float_as_int(e2.x) * 64 + j];
    float h3 = H[(size_t)__float_as_int(e3.x) * 64 + j];
    acc = fmaf(h0, e0.y, acc);
    acc = fmaf(h1, e1.y, acc);
    acc = fmaf(h2, e2.y, acc);
    acc = fmaf(h3, e3.y, acc);
  }
  for (; p < p1; ++p) {
    float2 e = ew[p];
    acc = fmaf(H[(size_t)__float_as_int(e.x) * 64 + j], e.y, acc);
  }
  out[(size_t)i * 64 + j] = acc;
}

// ---------------- BatchNorm ----------------

__global__ __launch_bounds__(256) void k_bnstats(const float* __restrict__ A,
                                                 float* __restrict__ stats, int n) {
  int j = threadIdx.x & 63;
  int r = threadIdx.x >> 6;
  float s = 0.f, s2 = 0.f;
  for (int i = blockIdx.x * 4 + r; i < n; i += gridDim.x * 4) {
    float v = A[(size_t)i * 64 + j];
    s += v;
    s2 += v * v;
  }
  __shared__ float ls[256], ls2[256];
  ls[threadIdx.x] = s;
  ls2[threadIdx.x] = s2;
  __syncthreads();
  if (threadIdx.x < 64) {
    float ts = ls[j] + ls[j + 64] + ls[j + 128] + ls[j + 192];
    float ts2 = ls2[j] + ls2[j + 64] + ls2[j + 128] + ls2[j + 192];
    atomicAdd(&stats[j], ts);
    atomicAdd(&stats[64 + j], ts2);
  }
}

__global__ __launch_bounds__(256) void k_bnapply(const float* __restrict__ A,
                                                 const float* __restrict__ stats,
                                                 const float* __restrict__ gamma,
                                                 const float* __restrict__ beta,
                                                 float* __restrict__ Hout, int n) {
  int j = threadIdx.x & 63;
  int i = blockIdx.x * 4 + (threadIdx.x >> 6);
  if (i >= n) return;
  float inv_n = 1.0f / (float)n;
  float mean = stats[j] * inv_n;
  float var = stats[64 + j] * inv_n - mean * mean;
  float scale = rsqrtf(var + BN_EPS) * gamma[j];
  float v = (A[(size_t)i * 64 + j] - mean) * scale + beta[j];
  Hout[(size_t)i * 64 + j] = fmaxf(v, 0.f);
}

// ---------------- launch ----------------

extern "C" void kernel_launch(void* const* d_in, const int* in_sizes, int n_in,
                              void* d_out, int out_size, void* d_ws, size_t ws_size,
                              hipStream_t stream) {
  const float* x     = (const float*)d_in[0];
  const int*   ei    = (const int*)d_in[1];
  const float* W1    = (const float*)d_in[2];
  const float* b1    = (const float*)d_in[3];
  const float* W2    = (const float*)d_in[4];
  const float* b2    = (const float*)d_in[5];
  const float* gamma = (const float*)d_in[6];
  const float* beta  = (const float*)d_in[7];
  float* out = (float*)d_out;

  const int N = in_sizes[0] / 128;   // 100000
  const int E = in_sizes[1] / 2;     // 1600000
  const int* src = ei;
  const int* dst = ei + E;

  const size_t Npad = ((size_t)N + 256) & ~(size_t)255;

  // workspace layout
  char* p = (char*)d_ws;
  float*  dinv    = (float*)p;      p += Npad * 4;
  int*    cnt     = (int*)p;        p += Npad * 4;
  int*    row_ptr = (int*)p;        p += Npad * 4;
  int*    blksum  = (int*)p;        p += 256 * 4;
  float2* ew      = (float2*)p;     p += (size_t)E * 8;
  float*  h       = (float*)p;      p += (size_t)N * 64 * 4;
  float*  agg     = (float*)p;      p += (size_t)N * 64 * 4;
  float*  stats   = (float*)p;      p += 128 * 4;

  int nb_n  = (N + 255) / 256;
  int nb_e  = (E + 255) / 256;
  int nb_n4 = (N + 3) / 4;
  int nb_t  = (N + 63) / 64;        // gemm tiles
  int nscan = (N + SCAN_CHUNK - 1) / SCAN_CHUNK;

  // ---- degree + dinv ----
  k_zero_int<<<nb_n, 256, 0, stream>>>(cnt, N);
  k_deg_int<<<nb_e, 256, 0, stream>>>(dst, cnt, E);
  k_dinv<<<nb_n, 256, 0, stream>>>(cnt, dinv, N);

  // ---- CSR build ----
  k_scan_local<<<nscan, 256, 0, stream>>>(cnt, row_ptr, blksum, N);
  k_scan_blk<<<1, 64, 0, stream>>>(blksum, nscan, row_ptr, N);
  k_scan_add<<<nscan, 256, 0, stream>>>(row_ptr, blksum, N);
  k_zero_int<<<nb_n, 256, 0, stream>>>(cnt, N);
  k_fill<<<nb_e, 256, 0, stream>>>(src, dst, dinv, row_ptr, cnt, ew, E);

  // ---- layer 1 ----
  k_gemm<128><<<nb_t, 256, 0, stream>>>(x, W1, h, N);
  k_gather<<<nb_n4, 256, 0, stream>>>(h, row_ptr, ew, dinv, b1, agg, N);

  // ---- batchnorm + relu -> h (reused) ----
  k_zero_f<<<1, 128, 0, stream>>>(stats, 128);
  k_bnstats<<<1024, 256, 0, stream>>>(agg, stats, N);
  k_bnapply<<<nb_n4, 256, 0, stream>>>(agg, stats, gamma, beta, h, N);

  // ---- layer 2 ----
  k_gemm<64><<<nb_t, 256, 0, stream>>>(h, W2, agg, N);
  k_gather<<<nb_n4, 256, 0, stream>>>(agg, row_ptr, ew, dinv, b2, out, N);
}

// Round 4
// 459.780 us; speedup vs baseline: 2.4776x; 1.0892x over previous
//
#include <hip/hip_runtime.h>

#define BN_EPS 1e-5f
#define SCAN_CHUNK 2048

// ---------------- utility ----------------

__global__ void k_zero_int(int* __restrict__ p, int n) {
  int i = blockIdx.x * blockDim.x + threadIdx.x;
  if (i < n) p[i] = 0;
}

__global__ void k_zero_f(float* __restrict__ p, int n) {
  int i = blockIdx.x * blockDim.x + threadIdx.x;
  if (i < n) p[i] = 0.0f;
}

// degree count; atomic old value doubles as this edge's rank within its dst bucket
__global__ void k_deg_rank(const int* __restrict__ dst, int* __restrict__ cnt,
                           int* __restrict__ rank, int E) {
  int e = blockIdx.x * blockDim.x + threadIdx.x;
  if (e < E) rank[e] = atomicAdd(&cnt[dst[e]], 1);
}

// dinv[i] = rsqrt(1 + deg[i])  (self-loop included)
__global__ void k_dinv(const int* __restrict__ cnt, float* __restrict__ dinv, int n) {
  int i = blockIdx.x * blockDim.x + threadIdx.x;
  if (i < n) dinv[i] = rsqrtf(1.0f + (float)cnt[i]);
}

// ---------------- exclusive scan (deg -> row_ptr) ----------------

__global__ __launch_bounds__(256) void k_scan_local(const int* __restrict__ deg,
                                                    int* __restrict__ row_ptr,
                                                    int* __restrict__ blksum, int n) {
  __shared__ int ts[256];
  int base = blockIdx.x * SCAN_CHUNK;
  int t = threadIdx.x;
  int idx0 = base + t * 8;
  int v[8];
  int s = 0;
#pragma unroll
  for (int k = 0; k < 8; ++k) {
    int i = idx0 + k;
    int d = (i < n) ? deg[i] : 0;
    v[k] = s;
    s += d;
  }
  int val = s;
  ts[t] = val;
  __syncthreads();
#pragma unroll
  for (int off = 1; off < 256; off <<= 1) {
    int add = (t >= off) ? ts[t - off] : 0;
    __syncthreads();
    val += add;
    ts[t] = val;
    __syncthreads();
  }
  int excl = val - s;
#pragma unroll
  for (int k = 0; k < 8; ++k) {
    int i = idx0 + k;
    if (i < n) row_ptr[i] = excl + v[k];
  }
  if (t == 255) blksum[blockIdx.x] = val;
}

__global__ void k_scan_blk(int* __restrict__ blksum, int nblk,
                           int* __restrict__ row_ptr, int n) {
  if (threadIdx.x == 0) {
    int run = 0;
    for (int i = 0; i < nblk; ++i) { int v = blksum[i]; blksum[i] = run; run += v; }
    row_ptr[n] = run;
  }
}

__global__ __launch_bounds__(256) void k_scan_add(int* __restrict__ row_ptr,
                                                  const int* __restrict__ blksum, int n) {
  int off = blksum[blockIdx.x];
  int base = blockIdx.x * SCAN_CHUNK;
  for (int k = threadIdx.x; k < SCAN_CHUNK; k += 256) {
    int i = base + k;
    if (i < n) row_ptr[i] += off;
  }
}

// CSR fill, atomic-free: col[row_ptr[d] + rank[e]] = src[e]
__global__ void k_fill(const int* __restrict__ src, const int* __restrict__ dst,
                       const int* __restrict__ rank, const int* __restrict__ row_ptr,
                       int* __restrict__ col, int E) {
  int e = blockIdx.x * blockDim.x + threadIdx.x;
  if (e >= E) return;
  col[row_ptr[dst[e]] + rank[e]] = src[e];
}

// ---------------- tiled GEMM: Y[n,64] = (X[n,K] @ W[K,64]) * dinv[row] ----------------
// One block per 64-row tile; 4x4 register tile per thread; row-scaled epilogue.
template<int K>
__global__ __launch_bounds__(256) void k_gemm(const float* __restrict__ X,
                                              const float* __restrict__ W,
                                              const float* __restrict__ dinv,
                                              float* __restrict__ Y, int n) {
  constexpr int XS = K + 4;
  __shared__ float Ws[K * 64];
  __shared__ float Xs[64 * XS];

  const int t = threadIdx.x;
  const int base = blockIdx.x * 64;

  {
    const float4* wv = (const float4*)W;
    float4* wsv = (float4*)Ws;
#pragma unroll
    for (int idx = t; idx < K * 16; idx += 256) wsv[idx] = wv[idx];
  }
  {
    constexpr int RV = K / 4;
    for (int idx = t; idx < 64 * RV; idx += 256) {
      int row = idx / RV, kk = idx % RV;
      float4 v = make_float4(0.f, 0.f, 0.f, 0.f);
      if (base + row < n) v = *(const float4*)(X + (size_t)(base + row) * K + kk * 4);
      *(float4*)(Xs + row * XS + kk * 4) = v;
    }
  }
  __syncthreads();

  const int tc = t & 15;
  const int tr = t >> 4;

  float acc[4][4];
#pragma unroll
  for (int r = 0; r < 4; ++r)
#pragma unroll
    for (int c = 0; c < 4; ++c) acc[r][c] = 0.f;

#pragma unroll 4
  for (int k = 0; k < K; k += 4) {
    float4 xr[4], wr[4];
#pragma unroll
    for (int r = 0; r < 4; ++r) xr[r] = *(const float4*)(Xs + (tr * 4 + r) * XS + k);
#pragma unroll
    for (int kk = 0; kk < 4; ++kk) wr[kk] = *(const float4*)(Ws + (k + kk) * 64 + tc * 4);
#pragma unroll
    for (int kk = 0; kk < 4; ++kk) {
#pragma unroll
      for (int r = 0; r < 4; ++r) {
        float xv = (kk == 0) ? xr[r].x : (kk == 1) ? xr[r].y : (kk == 2) ? xr[r].z : xr[r].w;
        acc[r][0] = fmaf(xv, wr[kk].x, acc[r][0]);
        acc[r][1] = fmaf(xv, wr[kk].y, acc[r][1]);
        acc[r][2] = fmaf(xv, wr[kk].z, acc[r][2]);
        acc[r][3] = fmaf(xv, wr[kk].w, acc[r][3]);
      }
    }
  }

#pragma unroll
  for (int r = 0; r < 4; ++r) {
    int i = base + tr * 4 + r;
    if (i < n) {
      float sc = dinv[i];
      float4 o = make_float4(acc[r][0] * sc, acc[r][1] * sc, acc[r][2] * sc, acc[r][3] * sc);
      *(float4*)(Y + (size_t)i * 64 + tc * 4) = o;
    }
  }
}

// ---------------- CSR gather aggregation (weight-free) ----------------
// Hs is pre-scaled by dinv[row]; out[i,j] = b[j] + dinv[i]*(Hs[i,j] + sum_p Hs[col[p],j])
__global__ __launch_bounds__(256) void k_gather(const float* __restrict__ Hs,
                                                const int* __restrict__ row_ptr,
                                                const int* __restrict__ col,
                                                const float* __restrict__ dinv,
                                                const float* __restrict__ b,
                                                float* __restrict__ out, int n) {
  int j = threadIdx.x & 63;
  int i = blockIdx.x * 4 + (threadIdx.x >> 6);
  if (i >= n) return;
  float acc = Hs[(size_t)i * 64 + j];
  int p0 = row_ptr[i], p1 = row_ptr[i + 1];
  int p = p0;
  for (; p + 3 < p1; p += 4) {
    int s0 = col[p], s1 = col[p + 1], s2 = col[p + 2], s3 = col[p + 3];
    float h0 = Hs[(size_t)s0 * 64 + j];
    float h1 = Hs[(size_t)s1 * 64 + j];
    float h2 = Hs[(size_t)s2 * 64 + j];
    float h3 = Hs[(size_t)s3 * 64 + j];
    acc += h0 + h1 + h2 + h3;
  }
  for (; p < p1; ++p) acc += Hs[(size_t)col[p] * 64 + j];
  out[(size_t)i * 64 + j] = b[j] + dinv[i] * acc;
}

// ---------------- BatchNorm ----------------

__global__ __launch_bounds__(256) void k_bnstats(const float* __restrict__ A,
                                                 float* __restrict__ stats, int n) {
  int j = threadIdx.x & 63;
  int r = threadIdx.x >> 6;
  float s = 0.f, s2 = 0.f;
  for (int i = blockIdx.x * 4 + r; i < n; i += gridDim.x * 4) {
    float v = A[(size_t)i * 64 + j];
    s += v;
    s2 += v * v;
  }
  __shared__ float ls[256], ls2[256];
  ls[threadIdx.x] = s;
  ls2[threadIdx.x] = s2;
  __syncthreads();
  if (threadIdx.x < 64) {
    float ts = ls[j] + ls[j + 64] + ls[j + 128] + ls[j + 192];
    float ts2 = ls2[j] + ls2[j + 64] + ls2[j + 128] + ls2[j + 192];
    atomicAdd(&stats[j], ts);
    atomicAdd(&stats[64 + j], ts2);
  }
}

__global__ __launch_bounds__(256) void k_bnapply(const float* __restrict__ A,
                                                 const float* __restrict__ stats,
                                                 const float* __restrict__ gamma,
                                                 const float* __restrict__ beta,
                                                 float* __restrict__ Hout, int n) {
  int j = threadIdx.x & 63;
  int i = blockIdx.x * 4 + (threadIdx.x >> 6);
  if (i >= n) return;
  float inv_n = 1.0f / (float)n;
  float mean = stats[j] * inv_n;
  float var = stats[64 + j] * inv_n - mean * mean;
  float scale = rsqrtf(var + BN_EPS) * gamma[j];
  float v = (A[(size_t)i * 64 + j] - mean) * scale + beta[j];
  Hout[(size_t)i * 64 + j] = fmaxf(v, 0.f);
}

// ---------------- launch ----------------

extern "C" void kernel_launch(void* const* d_in, const int* in_sizes, int n_in,
                              void* d_out, int out_size, void* d_ws, size_t ws_size,
                              hipStream_t stream) {
  const float* x     = (const float*)d_in[0];
  const int*   ei    = (const int*)d_in[1];
  const float* W1    = (const float*)d_in[2];
  const float* b1    = (const float*)d_in[3];
  const float* W2    = (const float*)d_in[4];
  const float* b2    = (const float*)d_in[5];
  const float* gamma = (const float*)d_in[6];
  const float* beta  = (const float*)d_in[7];
  float* out = (float*)d_out;

  const int N = in_sizes[0] / 128;   // 100000
  const int E = in_sizes[1] / 2;     // 1600000
  const int* src = ei;
  const int* dst = ei + E;

  const size_t Npad = ((size_t)N + 256) & ~(size_t)255;

  // workspace layout
  char* p = (char*)d_ws;
  float* dinv    = (float*)p;      p += Npad * 4;
  int*   cnt     = (int*)p;        p += Npad * 4;
  int*   row_ptr = (int*)p;        p += Npad * 4;
  int*   blksum  = (int*)p;        p += 256 * 4;
  int*   rank    = (int*)p;        p += (size_t)E * 4;
  int*   col     = (int*)p;        p += (size_t)E * 4;
  float* h       = (float*)p;      p += (size_t)N * 64 * 4;
  float* agg     = (float*)p;      p += (size_t)N * 64 * 4;
  float* stats   = (float*)p;      p += 128 * 4;

  int nb_n  = (N + 255) / 256;
  int nb_e  = (E + 255) / 256;
  int nb_n4 = (N + 3) / 4;
  int nb_t  = (N + 63) / 64;
  int nscan = (N + SCAN_CHUNK - 1) / SCAN_CHUNK;

  // ---- degree (+ per-edge rank) + dinv ----
  k_zero_int<<<nb_n, 256, 0, stream>>>(cnt, N);
  k_deg_rank<<<nb_e, 256, 0, stream>>>(dst, cnt, rank, E);
  k_dinv<<<nb_n, 256, 0, stream>>>(cnt, dinv, N);

  // ---- CSR build (atomic-free fill) ----
  k_scan_local<<<nscan, 256, 0, stream>>>(cnt, row_ptr, blksum, N);
  k_scan_blk<<<1, 64, 0, stream>>>(blksum, nscan, row_ptr, N);
  k_scan_add<<<nscan, 256, 0, stream>>>(row_ptr, blksum, N);
  k_fill<<<nb_e, 256, 0, stream>>>(src, dst, rank, row_ptr, col, E);

  // ---- layer 1: h = (x@W1)*dinv ; agg = b1 + dinv*(h_self + gathered) ----
  k_gemm<128><<<nb_t, 256, 0, stream>>>(x, W1, dinv, h, N);
  k_gather<<<nb_n4, 256, 0, stream>>>(h, row_ptr, col, dinv, b1, agg, N);

  // ---- batchnorm + relu -> h (reused as h2) ----
  k_zero_f<<<1, 128, 0, stream>>>(stats, 128);
  k_bnstats<<<1024, 256, 0, stream>>>(agg, stats, N);
  k_bnapply<<<nb_n4, 256, 0, stream>>>(agg, stats, gamma, beta, h, N);

  // ---- layer 2: g = (h2@W2)*dinv ; out = b2 + dinv*(g_self + gathered) ----
  k_gemm<64><<<nb_t, 256, 0, stream>>>(h, W2, dinv, agg, N);
  k_gather<<<nb_n4, 256, 0, stream>>>(agg, row_ptr, col, dinv, b2, out, N);
}

// Round 5
// 425.894 us; speedup vs baseline: 2.6748x; 1.0796x over previous
//
#include <hip/hip_runtime.h>

#define BN_EPS 1e-5f
#define SCAN_CHUNK 2048

// ---------------- bf16 helpers ----------------
__device__ __forceinline__ float bf2f(unsigned short u) {
  return __uint_as_float(((unsigned)u) << 16);
}
__device__ __forceinline__ unsigned short f2bf(float f) {
  unsigned b = __float_as_uint(f);
  b += 0x7FFFu + ((b >> 16) & 1u);   // round-to-nearest-even
  return (unsigned short)(b >> 16);
}

// ---------------- utility ----------------

__global__ void k_zero_int(int* __restrict__ p, int n) {
  int i = blockIdx.x * blockDim.x + threadIdx.x;
  if (i < n) p[i] = 0;
}

// degree count; atomic old value doubles as this edge's rank within its dst bucket
__global__ void k_deg_rank(const int* __restrict__ dst, int* __restrict__ cnt,
                           int* __restrict__ rank, int E) {
  int e = blockIdx.x * blockDim.x + threadIdx.x;
  if (e < E) rank[e] = atomicAdd(&cnt[dst[e]], 1);
}

// ---------------- exclusive scan (deg -> row_ptr), fused dinv ----------------

__global__ __launch_bounds__(256) void k_scan_local(const int* __restrict__ deg,
                                                    int* __restrict__ row_ptr,
                                                    int* __restrict__ blksum,
                                                    float* __restrict__ dinv, int n) {
  __shared__ int ts[256];
  int base = blockIdx.x * SCAN_CHUNK;
  int t = threadIdx.x;
  int idx0 = base + t * 8;
  int v[8];
  int s = 0;
#pragma unroll
  for (int k = 0; k < 8; ++k) {
    int i = idx0 + k;
    int d = (i < n) ? deg[i] : 0;
    if (i < n) dinv[i] = rsqrtf(1.0f + (float)d);   // self-loop included
    v[k] = s;
    s += d;
  }
  int val = s;
  ts[t] = val;
  __syncthreads();
#pragma unroll
  for (int off = 1; off < 256; off <<= 1) {
    int add = (t >= off) ? ts[t - off] : 0;
    __syncthreads();
    val += add;
    ts[t] = val;
    __syncthreads();
  }
  int excl = val - s;
#pragma unroll
  for (int k = 0; k < 8; ++k) {
    int i = idx0 + k;
    if (i < n) row_ptr[i] = excl + v[k];
  }
  if (t == 255) blksum[blockIdx.x] = val;
}

__global__ void k_scan_blk(int* __restrict__ blksum, int nblk,
                           int* __restrict__ row_ptr, int n,
                           float* __restrict__ stats) {
  // fused: zero the BN stats accumulators (used much later)
  for (int i = threadIdx.x; i < 128; i += 64) stats[i] = 0.f;
  if (threadIdx.x == 0) {
    int run = 0;
    for (int i = 0; i < nblk; ++i) { int v = blksum[i]; blksum[i] = run; run += v; }
    row_ptr[n] = run;
  }
}

__global__ __launch_bounds__(256) void k_scan_add(int* __restrict__ row_ptr,
                                                  const int* __restrict__ blksum, int n) {
  int off = blksum[blockIdx.x];
  int base = blockIdx.x * SCAN_CHUNK;
  for (int k = threadIdx.x; k < SCAN_CHUNK; k += 256) {
    int i = base + k;
    if (i < n) row_ptr[i] += off;
  }
}

// CSR fill, atomic-free: col[row_ptr[d] + rank[e]] = src[e]
__global__ void k_fill(const int* __restrict__ src, const int* __restrict__ dst,
                       const int* __restrict__ rank, const int* __restrict__ row_ptr,
                       int* __restrict__ col, int E) {
  int e = blockIdx.x * blockDim.x + threadIdx.x;
  if (e >= E) return;
  col[row_ptr[dst[e]] + rank[e]] = src[e];
}

// ---------------- tiled GEMM: Yb16[n,64] = op(X)[n,K] @ W[K,64] * dinv[row] ----------------
// op = identity, or (FUSE_BN) BatchNorm(stats)+ReLU applied while staging X.
// One block per 64-row tile; 4x4 register tile per thread; bf16 packed output.
template<int K, bool FUSE_BN>
__global__ __launch_bounds__(256) void k_gemm(const float* __restrict__ X,
                                              const float* __restrict__ W,
                                              const float* __restrict__ dinv,
                                              const float* __restrict__ stats,
                                              const float* __restrict__ gamma,
                                              const float* __restrict__ beta,
                                              unsigned short* __restrict__ Y,
                                              int n, float inv_n) {
  constexpr int XS = K + 4;
  __shared__ float Ws[K * 64];
  __shared__ float Xs[64 * XS];
  __shared__ float mean_s[64], scl_s[64], bt_s[64];

  const int t = threadIdx.x;
  const int base = blockIdx.x * 64;

  if (FUSE_BN) {
    if (t < 64) {
      float mean = stats[t] * inv_n;
      float var = stats[64 + t] * inv_n - mean * mean;
      mean_s[t] = mean;
      scl_s[t] = rsqrtf(var + BN_EPS) * gamma[t];
      bt_s[t] = beta[t];
    }
    __syncthreads();
  }

  {
    const float4* wv = (const float4*)W;
    float4* wsv = (float4*)Ws;
#pragma unroll
    for (int idx = t; idx < K * 16; idx += 256) wsv[idx] = wv[idx];
  }
  {
    constexpr int RV = K / 4;
    for (int idx = t; idx < 64 * RV; idx += 256) {
      int row = idx / RV, kk = idx % RV;
      float4 v = make_float4(0.f, 0.f, 0.f, 0.f);
      if (base + row < n) {
        v = *(const float4*)(X + (size_t)(base + row) * K + kk * 4);
        if (FUSE_BN) {
          int k0 = kk * 4;
          v.x = fmaxf(fmaf(v.x - mean_s[k0 + 0], scl_s[k0 + 0], bt_s[k0 + 0]), 0.f);
          v.y = fmaxf(fmaf(v.y - mean_s[k0 + 1], scl_s[k0 + 1], bt_s[k0 + 1]), 0.f);
          v.z = fmaxf(fmaf(v.z - mean_s[k0 + 2], scl_s[k0 + 2], bt_s[k0 + 2]), 0.f);
          v.w = fmaxf(fmaf(v.w - mean_s[k0 + 3], scl_s[k0 + 3], bt_s[k0 + 3]), 0.f);
        }
      }
      *(float4*)(Xs + row * XS + kk * 4) = v;
    }
  }
  __syncthreads();

  const int tc = t & 15;
  const int tr = t >> 4;

  float acc[4][4];
#pragma unroll
  for (int r = 0; r < 4; ++r)
#pragma unroll
    for (int c = 0; c < 4; ++c) acc[r][c] = 0.f;

#pragma unroll 4
  for (int k = 0; k < K; k += 4) {
    float4 xr[4], wr[4];
#pragma unroll
    for (int r = 0; r < 4; ++r) xr[r] = *(const float4*)(Xs + (tr * 4 + r) * XS + k);
#pragma unroll
    for (int kk = 0; kk < 4; ++kk) wr[kk] = *(const float4*)(Ws + (k + kk) * 64 + tc * 4);
#pragma unroll
    for (int kk = 0; kk < 4; ++kk) {
#pragma unroll
      for (int r = 0; r < 4; ++r) {
        float xv = (kk == 0) ? xr[r].x : (kk == 1) ? xr[r].y : (kk == 2) ? xr[r].z : xr[r].w;
        acc[r][0] = fmaf(xv, wr[kk].x, acc[r][0]);
        acc[r][1] = fmaf(xv, wr[kk].y, acc[r][1]);
        acc[r][2] = fmaf(xv, wr[kk].z, acc[r][2]);
        acc[r][3] = fmaf(xv, wr[kk].w, acc[r][3]);
      }
    }
  }

#pragma unroll
  for (int r = 0; r < 4; ++r) {
    int i = base + tr * 4 + r;
    if (i < n) {
      float sc = dinv[i];
      ushort4 o;
      o.x = f2bf(acc[r][0] * sc);
      o.y = f2bf(acc[r][1] * sc);
      o.z = f2bf(acc[r][2] * sc);
      o.w = f2bf(acc[r][3] * sc);
      *(ushort4*)(Y + (size_t)i * 64 + tc * 4) = o;
    }
  }
}

// ---------------- CSR gather aggregation (bf16 table, weight-free) ----------------
// Hs is bf16, pre-scaled by dinv[row]; out[i,j] = b[j] + dinv[i]*(Hs[i,j] + sum_p Hs[col[p],j])
__global__ __launch_bounds__(256) void k_gather(const unsigned short* __restrict__ Hs,
                                                const int* __restrict__ row_ptr,
                                                const int* __restrict__ col,
                                                const float* __restrict__ dinv,
                                                const float* __restrict__ b,
                                                float* __restrict__ out, int n) {
  int j = threadIdx.x & 63;
  int i = blockIdx.x * 4 + (threadIdx.x >> 6);
  if (i >= n) return;
  float acc = bf2f(Hs[(size_t)i * 64 + j]);
  int p0 = row_ptr[i], p1 = row_ptr[i + 1];
  int p = p0;
  for (; p + 8 <= p1; p += 8) {
    int s0 = col[p], s1 = col[p + 1], s2 = col[p + 2], s3 = col[p + 3];
    int s4 = col[p + 4], s5 = col[p + 5], s6 = col[p + 6], s7 = col[p + 7];
    float h0 = bf2f(Hs[(size_t)s0 * 64 + j]);
    float h1 = bf2f(Hs[(size_t)s1 * 64 + j]);
    float h2 = bf2f(Hs[(size_t)s2 * 64 + j]);
    float h3 = bf2f(Hs[(size_t)s3 * 64 + j]);
    float h4 = bf2f(Hs[(size_t)s4 * 64 + j]);
    float h5 = bf2f(Hs[(size_t)s5 * 64 + j]);
    float h6 = bf2f(Hs[(size_t)s6 * 64 + j]);
    float h7 = bf2f(Hs[(size_t)s7 * 64 + j]);
    acc += ((h0 + h1) + (h2 + h3)) + ((h4 + h5) + (h6 + h7));
  }
  for (; p < p1; ++p) acc += bf2f(Hs[(size_t)col[p] * 64 + j]);
  out[(size_t)i * 64 + j] = fmaf(dinv[i], acc, b[j]);
}

// ---------------- BatchNorm stats ----------------

__global__ __launch_bounds__(256) void k_bnstats(const float* __restrict__ A,
                                                 float* __restrict__ stats, int n) {
  int j = threadIdx.x & 63;
  int r = threadIdx.x >> 6;
  float s = 0.f, s2 = 0.f;
  for (int i = blockIdx.x * 4 + r; i < n; i += gridDim.x * 4) {
    float v = A[(size_t)i * 64 + j];
    s += v;
    s2 += v * v;
  }
  __shared__ float ls[256], ls2[256];
  ls[threadIdx.x] = s;
  ls2[threadIdx.x] = s2;
  __syncthreads();
  if (threadIdx.x < 64) {
    float ts = ls[j] + ls[j + 64] + ls[j + 128] + ls[j + 192];
    float ts2 = ls2[j] + ls2[j + 64] + ls2[j + 128] + ls2[j + 192];
    atomicAdd(&stats[j], ts);
    atomicAdd(&stats[64 + j], ts2);
  }
}

// ---------------- launch ----------------

extern "C" void kernel_launch(void* const* d_in, const int* in_sizes, int n_in,
                              void* d_out, int out_size, void* d_ws, size_t ws_size,
                              hipStream_t stream) {
  const float* x     = (const float*)d_in[0];
  const int*   ei    = (const int*)d_in[1];
  const float* W1    = (const float*)d_in[2];
  const float* b1    = (const float*)d_in[3];
  const float* W2    = (const float*)d_in[4];
  const float* b2    = (const float*)d_in[5];
  const float* gamma = (const float*)d_in[6];
  const float* beta  = (const float*)d_in[7];
  float* out = (float*)d_out;

  const int N = in_sizes[0] / 128;   // 100000
  const int E = in_sizes[1] / 2;     // 1600000
  const int* src = ei;
  const int* dst = ei + E;

  const size_t Npad = ((size_t)N + 256) & ~(size_t)255;

  // workspace layout
  char* p = (char*)d_ws;
  float* dinv    = (float*)p;              p += Npad * 4;
  int*   cnt     = (int*)p;                p += Npad * 4;
  int*   row_ptr = (int*)p;                p += Npad * 4;
  int*   blksum  = (int*)p;                p += 256 * 4;
  int*   rank    = (int*)p;                p += (size_t)E * 4;
  int*   col     = (int*)p;                p += (size_t)E * 4;
  unsigned short* h16 = (unsigned short*)p; p += (size_t)N * 64 * 2;  // bf16 table (both layers)
  float* agg     = (float*)p;              p += (size_t)N * 64 * 4;
  float* stats   = (float*)p;              p += 128 * 4;

  int nb_n  = (N + 255) / 256;
  int nb_e  = (E + 255) / 256;
  int nb_n4 = (N + 3) / 4;
  int nb_t  = (N + 63) / 64;
  int nscan = (N + SCAN_CHUNK - 1) / SCAN_CHUNK;
  float inv_n = 1.0f / (float)N;

  // ---- degree (+ per-edge rank) ----
  k_zero_int<<<nb_n, 256, 0, stream>>>(cnt, N);
  k_deg_rank<<<nb_e, 256, 0, stream>>>(dst, cnt, rank, E);

  // ---- CSR build (dinv fused into scan; stats zero fused into scan_blk) ----
  k_scan_local<<<nscan, 256, 0, stream>>>(cnt, row_ptr, blksum, dinv, N);
  k_scan_blk<<<1, 64, 0, stream>>>(blksum, nscan, row_ptr, N, stats);
  k_scan_add<<<nscan, 256, 0, stream>>>(row_ptr, blksum, N);
  k_fill<<<nb_e, 256, 0, stream>>>(src, dst, rank, row_ptr, col, E);

  // ---- layer 1: h16 = bf16((x@W1)*dinv) ; agg = b1 + dinv*(self + gathered) ----
  k_gemm<128, false><<<nb_t, 256, 0, stream>>>(x, W1, dinv, nullptr, nullptr, nullptr,
                                               h16, N, inv_n);
  k_gather<<<nb_n4, 256, 0, stream>>>(h16, row_ptr, col, dinv, b1, agg, N);

  // ---- BN stats ----
  k_bnstats<<<1024, 256, 0, stream>>>(agg, stats, N);

  // ---- layer 2: h16 = bf16((BN+ReLU(agg)@W2)*dinv) ; out = b2 + dinv*(self + gathered) ----
  k_gemm<64, true><<<nb_t, 256, 0, stream>>>(agg, W2, dinv, stats, gamma, beta,
                                             h16, N, inv_n);
  k_gather<<<nb_n4, 256, 0, stream>>>(h16, row_ptr, col, dinv, b2, out, N);
}